// Round 2
// baseline (310.661 us; speedup 1.0000x reference)
//
#include <hip/hip_runtime.h>

// LocalChargeEnergy:
//   lin  = f0@w0 + (f1@w1 + b1) + (f2@w2 + b2)          [n_atoms]
//   e    = (lin * charge)^2 + lin                        [n_atoms]
//   mol  = segment_sum(e, mol_index, n_mol)              [n_mol]
// Outputs concatenated: mol (n_mol floats) then e (n_atoms floats).
//
// Memory-bound: 1.536 GB feature reads dominate. 32 lanes per atom,
// float4 coalesced loads, shfl-xor reduce, atomicAdd for segment sum.

__global__ void zero_kernel(float* __restrict__ p, int n) {
    int i = blockIdx.x * blockDim.x + threadIdx.x;
    if (i < n) p[i] = 0.0f;
}

__global__ void __launch_bounds__(256)
charge_energy_kernel(const float* __restrict__ charges,
                     const float* __restrict__ f0,
                     const float* __restrict__ f1,
                     const float* __restrict__ f2,
                     const int*   __restrict__ mol_index,
                     const float* __restrict__ w0,
                     const float* __restrict__ w1,
                     const float* __restrict__ w2,
                     const float* __restrict__ b1p,
                     const float* __restrict__ b2p,
                     float* __restrict__ mol_out,    // [n_mol], pre-zeroed
                     float* __restrict__ atom_out,   // [n_atoms]
                     int n_atoms)
{
    const int lane32  = threadIdx.x & 31;          // 32 threads cooperate per atom
    const int group   = threadIdx.x >> 5;          // group within block
    const int gpb     = blockDim.x >> 5;           // groups per block (8 for 256)
    const float bias  = b1p[0] + b2p[0];

    // Per-lane weight chunks (float4), hoisted out of the loop.
    const float4 w0c = reinterpret_cast<const float4*>(w0)[lane32];
    const float4 w1c = reinterpret_cast<const float4*>(w1)[lane32];
    const float4 w2c = reinterpret_cast<const float4*>(w2)[lane32];

    for (long long atom = (long long)blockIdx.x * gpb + group;
         atom < n_atoms;
         atom += (long long)gridDim.x * gpb) {

        const long long row = atom * 128;
        const float4 a0 = reinterpret_cast<const float4*>(f0 + row)[lane32];
        const float4 a1 = reinterpret_cast<const float4*>(f1 + row)[lane32];
        const float4 a2 = reinterpret_cast<const float4*>(f2 + row)[lane32];

        float partial = a0.x * w0c.x + a0.y * w0c.y + a0.z * w0c.z + a0.w * w0c.w
                      + a1.x * w1c.x + a1.y * w1c.y + a1.z * w1c.z + a1.w * w1c.w
                      + a2.x * w2c.x + a2.y * w2c.y + a2.z * w2c.z + a2.w * w2c.w;

        // Reduce across the 32-lane group (xor masks <32 stay in-group on wave64).
        #pragma unroll
        for (int m = 16; m >= 1; m >>= 1)
            partial += __shfl_xor(partial, m, 64);

        if (lane32 == 0) {
            const float lin = partial + bias;
            const float c   = charges[atom];
            const float lc  = lin * c;
            const float e   = lc * lc + lin;
            atom_out[atom] = e;
            atomicAdd(&mol_out[mol_index[atom]], e);
        }
    }
}

extern "C" void kernel_launch(void* const* d_in, const int* in_sizes, int n_in,
                              void* d_out, int out_size, void* d_ws, size_t ws_size,
                              hipStream_t stream) {
    const float* charges   = (const float*)d_in[0];
    const float* f0        = (const float*)d_in[1];
    const float* f1        = (const float*)d_in[2];
    const float* f2        = (const float*)d_in[3];
    const int*   mol_index = (const int*)  d_in[4];
    // d_in[5] = n_molecules (scalar on device; derive on host instead)
    const float* w0        = (const float*)d_in[6];
    const float* w1        = (const float*)d_in[7];
    const float* w2        = (const float*)d_in[8];
    const float* b1p       = (const float*)d_in[9];
    const float* b2p       = (const float*)d_in[10];

    const int n_atoms = in_sizes[0];          // charges element count
    const int n_mol   = out_size - n_atoms;   // outputs are [mol | atom]

    float* mol_out  = (float*)d_out;
    float* atom_out = mol_out + n_mol;

    // Zero the molecule accumulators every call (harness never re-poisons).
    {
        int blocks = (n_mol + 255) / 256;
        hipLaunchKernelGGL(zero_kernel, dim3(blocks), dim3(256), 0, stream,
                           mol_out, n_mol);
    }

    // Memory-bound: cap grid, grid-stride. 2048 blocks x 256 thr = 8 waves worth
    // of atom-groups per block; ~15 iterations each over 1M atoms.
    const int blocks = 2048;
    hipLaunchKernelGGL(charge_energy_kernel, dim3(blocks), dim3(256), 0, stream,
                       charges, f0, f1, f2, mol_index, w0, w1, w2, b1p, b2p,
                       mol_out, atom_out, n_atoms);
}

// Round 4
// 308.919 us; speedup vs baseline: 1.0056x; 1.0056x over previous
//
#include <hip/hip_runtime.h>

// LocalChargeEnergy:
//   lin  = f0@w0 + (f1@w1 + b1) + (f2@w2 + b2)          [n_atoms]
//   e    = (lin * charge)^2 + lin                        [n_atoms]
//   mol  = segment_sum(e, mol_index, n_mol)              [n_mol]
// Outputs concatenated: mol (n_mol floats) then e (n_atoms floats).
//
// Memory-bound (1.536 GB feature reads). One WAVE per contiguous chunk of
// atoms: lanes 0-31 = atom i, lanes 32-63 = atom i+1 -> each float4 load
// instruction covers 1 KB contiguous (2 rows). mol_index is sorted, so the
// wave run-length-accumulates energies per molecule in a register and emits
// ~1 atomicAdd per molecule-run (~57K total vs 1M) -- kills the atomic
// line ping-pong seen as 36 MB WRITE_SIZE in round 2.

__global__ void zero_kernel(float* __restrict__ p, int n) {
    int i = blockIdx.x * blockDim.x + threadIdx.x;
    if (i < n) p[i] = 0.0f;
}

__global__ void __launch_bounds__(256)
charge_energy_kernel(const float* __restrict__ charges,
                     const float* __restrict__ f0,
                     const float* __restrict__ f1,
                     const float* __restrict__ f2,
                     const int*   __restrict__ mol_index,
                     const float* __restrict__ w0,
                     const float* __restrict__ w1,
                     const float* __restrict__ w2,
                     const float* __restrict__ b1p,
                     const float* __restrict__ b2p,
                     float* __restrict__ mol_out,    // [n_mol], pre-zeroed
                     float* __restrict__ atom_out,   // [n_atoms]
                     int n_atoms,
                     int chunk)                      // atoms per wave, even
{
    const int lane   = threadIdx.x & 63;
    const int lane32 = lane & 31;
    const long long wid = (long long)blockIdx.x * (blockDim.x >> 6) + (threadIdx.x >> 6);

    long long a0 = wid * (long long)chunk;
    if (a0 >= n_atoms) return;
    long long a1 = a0 + chunk;
    if (a1 > n_atoms) a1 = n_atoms;

    const float bias = b1p[0] + b2p[0];
    // Per-lane weight chunk; lanes 0-31 and 32-63 use the same 32 float4s.
    const float4 w0c = reinterpret_cast<const float4*>(w0)[lane32];
    const float4 w1c = reinterpret_cast<const float4*>(w1)[lane32];
    const float4 w2c = reinterpret_cast<const float4*>(w2)[lane32];

    int   cur_mol = -1;     // run-length state (meaningful on lane 0 only)
    float cur_sum = 0.0f;

    for (long long a = a0; a < a1; a += 2) {
        // Small broadcast loads (same addr across wave -> 1 transaction).
        const float2 cc = *reinterpret_cast<const float2*>(charges + a);
        const int2   mm = *reinterpret_cast<const int2*>(mol_index + a);

        // 64 lanes x 16 B = 1 KB contiguous = rows a and a+1 of each array.
        const float4 x0 = (reinterpret_cast<const float4*>(f0) + a * 32)[lane];
        const float4 x1 = (reinterpret_cast<const float4*>(f1) + a * 32)[lane];
        const float4 x2 = (reinterpret_cast<const float4*>(f2) + a * 32)[lane];

        float partial = x0.x * w0c.x + x0.y * w0c.y + x0.z * w0c.z + x0.w * w0c.w
                      + x1.x * w1c.x + x1.y * w1c.y + x1.z * w1c.z + x1.w * w1c.w
                      + x2.x * w2c.x + x2.y * w2c.y + x2.z * w2c.z + x2.w * w2c.w;

        // Reduce within each 32-lane half (xor masks <32 stay in-half).
        #pragma unroll
        for (int m = 16; m >= 1; m >>= 1)
            partial += __shfl_xor(partial, m, 64);

        const float sA = __shfl(partial, 0, 64);   // sum for atom a
        const float sB = __shfl(partial, 32, 64);  // sum for atom a+1

        if (lane == 0) {
            const float lin0 = sA + bias;
            const float lin1 = sB + bias;
            const float t0 = lin0 * cc.x;
            const float t1 = lin1 * cc.y;
            const float e0 = t0 * t0 + lin0;
            const float e1 = t1 * t1 + lin1;
            *reinterpret_cast<float2*>(atom_out + a) = make_float2(e0, e1);

            // Run-length segment accumulation (mol_index sorted).
            if (mm.x != cur_mol) {
                if (cur_mol >= 0) atomicAdd(&mol_out[cur_mol], cur_sum);
                cur_mol = mm.x; cur_sum = e0;
            } else {
                cur_sum += e0;
            }
            if (mm.y != cur_mol) {
                atomicAdd(&mol_out[cur_mol], cur_sum);
                cur_mol = mm.y; cur_sum = e1;
            } else {
                cur_sum += e1;
            }
        }
    }
    if (lane == 0 && cur_mol >= 0)
        atomicAdd(&mol_out[cur_mol], cur_sum);
}

extern "C" void kernel_launch(void* const* d_in, const int* in_sizes, int n_in,
                              void* d_out, int out_size, void* d_ws, size_t ws_size,
                              hipStream_t stream) {
    const float* charges   = (const float*)d_in[0];
    const float* f0        = (const float*)d_in[1];
    const float* f1        = (const float*)d_in[2];
    const float* f2        = (const float*)d_in[3];
    const int*   mol_index = (const int*)  d_in[4];
    // d_in[5] = n_molecules (device scalar; derived on host instead)
    const float* w0        = (const float*)d_in[6];
    const float* w1        = (const float*)d_in[7];
    const float* w2        = (const float*)d_in[8];
    const float* b1p       = (const float*)d_in[9];
    const float* b2p       = (const float*)d_in[10];

    const int n_atoms = in_sizes[0];          // charges element count
    const int n_mol   = out_size - n_atoms;   // outputs are [mol | atom]

    float* mol_out  = (float*)d_out;
    float* atom_out = mol_out + n_mol;

    // Zero the molecule accumulators every call (harness never re-poisons).
    {
        int blocks = (n_mol + 255) / 256;
        hipLaunchKernelGGL(zero_kernel, dim3(blocks), dim3(256), 0, stream,
                           mol_out, n_mol);
    }

    // 2048 blocks x 4 waves = 8192 waves = exactly the 256CU x 32wave capacity.
    const int blocks  = 2048;
    const int n_waves = blocks * (256 / 64);
    int chunk = (n_atoms + n_waves - 1) / n_waves;
    chunk = (chunk + 1) & ~1;                 // even so float2/int2 stay aligned

    hipLaunchKernelGGL(charge_energy_kernel, dim3(blocks), dim3(256), 0, stream,
                       charges, f0, f1, f2, mol_index, w0, w1, w2, b1p, b2p,
                       mol_out, atom_out, n_atoms, chunk);
}

// Round 5
// 268.282 us; speedup vs baseline: 1.1580x; 1.1515x over previous
//
#include <hip/hip_runtime.h>

// LocalChargeEnergy:
//   lin  = f0@w0 + (f1@w1 + b1) + (f2@w2 + b2)          [n_atoms]
//   e    = (lin * charge)^2 + lin                        [n_atoms]
//   mol  = segment_sum(e, mol_index, n_mol)              [n_mol]
// Outputs concatenated: mol (n_mol floats) then e (n_atoms floats).
//
// Pure streaming-BW regime (round-4 counters: 5.0 TB/s delivered, VALUBusy
// 8.7%, atomics proven non-limiting). This round: nontemporal feature loads
// (zero-reuse streams; skip L2 allocation) + 4-atoms-per-iteration unroll
// (6 independent dwordx4 loads in flight per wave before the reduce chains).

typedef float f32x4 __attribute__((ext_vector_type(4)));

__global__ void zero_kernel(float* __restrict__ p, int n) {
    int i = blockIdx.x * blockDim.x + threadIdx.x;
    if (i < n) p[i] = 0.0f;
}

__device__ __forceinline__ float dot12(const f32x4 a, const f32x4 b, const f32x4 c,
                                       const f32x4 wa, const f32x4 wb, const f32x4 wc) {
    return a.x * wa.x + a.y * wa.y + a.z * wa.z + a.w * wa.w
         + b.x * wb.x + b.y * wb.y + b.z * wb.z + b.w * wb.w
         + c.x * wc.x + c.y * wc.y + c.z * wc.z + c.w * wc.w;
}

__global__ void __launch_bounds__(256)
charge_energy_kernel(const float* __restrict__ charges,
                     const float* __restrict__ f0,
                     const float* __restrict__ f1,
                     const float* __restrict__ f2,
                     const int*   __restrict__ mol_index,
                     const float* __restrict__ w0,
                     const float* __restrict__ w1,
                     const float* __restrict__ w2,
                     const float* __restrict__ b1p,
                     const float* __restrict__ b2p,
                     float* __restrict__ mol_out,    // [n_mol], pre-zeroed
                     float* __restrict__ atom_out,   // [n_atoms]
                     int n_atoms,
                     int chunk)                      // atoms per wave, mult of 4
{
    const int lane   = threadIdx.x & 63;
    const int lane32 = lane & 31;
    const long long wid = (long long)blockIdx.x * (blockDim.x >> 6) + (threadIdx.x >> 6);

    long long a0 = wid * (long long)chunk;
    if (a0 >= n_atoms) return;
    long long a1 = a0 + chunk;
    if (a1 > n_atoms) a1 = n_atoms;

    const float bias = b1p[0] + b2p[0];
    const f32x4 w0c = reinterpret_cast<const f32x4*>(w0)[lane32];
    const f32x4 w1c = reinterpret_cast<const f32x4*>(w1)[lane32];
    const f32x4 w2c = reinterpret_cast<const f32x4*>(w2)[lane32];

    int   cur_mol = -1;     // run-length state (meaningful on lane 0 only)
    float cur_sum = 0.0f;

    long long a = a0;
    // Main loop: 4 atoms per iteration. Lanes 0-31 = even row, 32-63 = odd row;
    // each trio of loads covers 1 KB contiguous; two trios -> 6 KB in flight.
    for (; a + 4 <= a1; a += 4) {
        const f32x4* p0 = reinterpret_cast<const f32x4*>(f0) + a * 32;
        const f32x4* p1 = reinterpret_cast<const f32x4*>(f1) + a * 32;
        const f32x4* p2 = reinterpret_cast<const f32x4*>(f2) + a * 32;

        const f32x4 xa0 = __builtin_nontemporal_load(p0 + lane);        // rows a, a+1
        const f32x4 xa1 = __builtin_nontemporal_load(p1 + lane);
        const f32x4 xa2 = __builtin_nontemporal_load(p2 + lane);
        const f32x4 xb0 = __builtin_nontemporal_load(p0 + 64 + lane);   // rows a+2, a+3
        const f32x4 xb1 = __builtin_nontemporal_load(p1 + 64 + lane);
        const f32x4 xb2 = __builtin_nontemporal_load(p2 + 64 + lane);

        const float4 cc = *reinterpret_cast<const float4*>(charges + a);
        const int4   mm = *reinterpret_cast<const int4*>(mol_index + a);

        float pA = dot12(xa0, xa1, xa2, w0c, w1c, w2c);
        float pB = dot12(xb0, xb1, xb2, w0c, w1c, w2c);

        // Two independent 5-step reduces (xor masks <32 stay within each half).
        #pragma unroll
        for (int m = 16; m >= 1; m >>= 1) {
            pA += __shfl_xor(pA, m, 64);
            pB += __shfl_xor(pB, m, 64);
        }
        const float s1 = __shfl(pA, 32, 64);   // row a+1 sum
        const float s3 = __shfl(pB, 32, 64);   // row a+3 sum

        if (lane == 0) {
            const float lin0 = pA + bias, lin1 = s1 + bias;
            const float lin2 = pB + bias, lin3 = s3 + bias;
            const float t0 = lin0 * cc.x, t1 = lin1 * cc.y;
            const float t2 = lin2 * cc.z, t3 = lin3 * cc.w;
            const float e0 = t0 * t0 + lin0, e1 = t1 * t1 + lin1;
            const float e2 = t2 * t2 + lin2, e3 = t3 * t3 + lin3;
            *reinterpret_cast<float4*>(atom_out + a) = make_float4(e0, e1, e2, e3);

            // Run-length segment accumulation (mol_index sorted).
            const int   ms[4] = {mm.x, mm.y, mm.z, mm.w};
            const float es[4] = {e0, e1, e2, e3};
            #pragma unroll
            for (int k = 0; k < 4; ++k) {
                if (ms[k] != cur_mol) {
                    if (cur_mol >= 0) atomicAdd(&mol_out[cur_mol], cur_sum);
                    cur_mol = ms[k]; cur_sum = es[k];
                } else {
                    cur_sum += es[k];
                }
            }
        }
    }
    // 2-atom tail.
    if (a + 2 <= a1) {
        const f32x4 x0 = (reinterpret_cast<const f32x4*>(f0) + a * 32)[lane];
        const f32x4 x1 = (reinterpret_cast<const f32x4*>(f1) + a * 32)[lane];
        const f32x4 x2 = (reinterpret_cast<const f32x4*>(f2) + a * 32)[lane];
        const float2 cc = *reinterpret_cast<const float2*>(charges + a);
        const int2   mm = *reinterpret_cast<const int2*>(mol_index + a);
        float p = dot12(x0, x1, x2, w0c, w1c, w2c);
        #pragma unroll
        for (int m = 16; m >= 1; m >>= 1) p += __shfl_xor(p, m, 64);
        const float sB = __shfl(p, 32, 64);
        if (lane == 0) {
            const float lin0 = p + bias, lin1 = sB + bias;
            const float t0 = lin0 * cc.x, t1 = lin1 * cc.y;
            const float e0 = t0 * t0 + lin0, e1 = t1 * t1 + lin1;
            *reinterpret_cast<float2*>(atom_out + a) = make_float2(e0, e1);
            if (mm.x != cur_mol) {
                if (cur_mol >= 0) atomicAdd(&mol_out[cur_mol], cur_sum);
                cur_mol = mm.x; cur_sum = e0;
            } else cur_sum += e0;
            if (mm.y != cur_mol) {
                atomicAdd(&mol_out[cur_mol], cur_sum);
                cur_mol = mm.y; cur_sum = e1;
            } else cur_sum += e1;
        }
        a += 2;
    }
    // 1-atom tail (n_atoms odd): both wave halves load the same row.
    if (a < a1) {
        const f32x4 x0 = (reinterpret_cast<const f32x4*>(f0) + a * 32)[lane32];
        const f32x4 x1 = (reinterpret_cast<const f32x4*>(f1) + a * 32)[lane32];
        const f32x4 x2 = (reinterpret_cast<const f32x4*>(f2) + a * 32)[lane32];
        float p = dot12(x0, x1, x2, w0c, w1c, w2c);
        #pragma unroll
        for (int m = 16; m >= 1; m >>= 1) p += __shfl_xor(p, m, 64);
        if (lane == 0) {
            const float lin = p + bias;
            const float t = lin * charges[a];
            const float e = t * t + lin;
            atom_out[a] = e;
            const int mi = mol_index[a];
            if (mi != cur_mol) {
                if (cur_mol >= 0) atomicAdd(&mol_out[cur_mol], cur_sum);
                cur_mol = mi; cur_sum = e;
            } else cur_sum += e;
        }
    }
    if (lane == 0 && cur_mol >= 0)
        atomicAdd(&mol_out[cur_mol], cur_sum);
}

extern "C" void kernel_launch(void* const* d_in, const int* in_sizes, int n_in,
                              void* d_out, int out_size, void* d_ws, size_t ws_size,
                              hipStream_t stream) {
    const float* charges   = (const float*)d_in[0];
    const float* f0        = (const float*)d_in[1];
    const float* f1        = (const float*)d_in[2];
    const float* f2        = (const float*)d_in[3];
    const int*   mol_index = (const int*)  d_in[4];
    // d_in[5] = n_molecules (device scalar; derived on host instead)
    const float* w0        = (const float*)d_in[6];
    const float* w1        = (const float*)d_in[7];
    const float* w2        = (const float*)d_in[8];
    const float* b1p       = (const float*)d_in[9];
    const float* b2p       = (const float*)d_in[10];

    const int n_atoms = in_sizes[0];          // charges element count
    const int n_mol   = out_size - n_atoms;   // outputs are [mol | atom]

    float* mol_out  = (float*)d_out;
    float* atom_out = mol_out + n_mol;

    // Zero the molecule accumulators every call (harness never re-poisons).
    {
        int blocks = (n_mol + 255) / 256;
        hipLaunchKernelGGL(zero_kernel, dim3(blocks), dim3(256), 0, stream,
                           mol_out, n_mol);
    }

    // 2048 blocks x 4 waves = 8192 waves = 256CU x 32-wave capacity.
    const int blocks  = 2048;
    const int n_waves = blocks * (256 / 64);
    int chunk = (n_atoms + n_waves - 1) / n_waves;
    chunk = (chunk + 3) & ~3;                 // mult of 4 for float4/int4 alignment

    hipLaunchKernelGGL(charge_energy_kernel, dim3(blocks), dim3(256), 0, stream,
                       charges, f0, f1, f2, mol_index, w0, w1, w2, b1p, b2p,
                       mol_out, atom_out, n_atoms, chunk);
}